// Round 2
// baseline (268.083 us; speedup 1.0000x reference)
//
#include <hip/hip_runtime.h>
#include <hip/hip_bf16.h>
#include <math.h>

#define Bdim 32
#define Adim 256
#define Ndim 64
#define Gdim 50
#define Fdim 128

typedef __attribute__((ext_vector_type(8)))  short short8;
typedef __attribute__((ext_vector_type(16))) float floatx16;

__device__ __forceinline__ unsigned short f2bf_u(float x) {
    __hip_bfloat16 h = __float2bfloat16(x);
    return __builtin_bit_cast(unsigned short, h);
}
__device__ __forceinline__ unsigned pk2bf(float a, float b) {
    return (unsigned)f2bf_u(a) | ((unsigned)f2bf_u(b) << 16);
}
__device__ __forceinline__ float bf2f(unsigned short v) {
    return __builtin_bit_cast(float, ((unsigned)v) << 16);
}
// shifted softplus: 6-op form (abs/neg fold into mul modifiers; fma folds ln2 shift)
__device__ __forceinline__ float sspf(float v) {
    float t = __expf(-fabsf(v));                    // v_mul(-|v|*log2e) + v_exp
    return fmaxf(v, 0.0f) +
           fmaf(__log2f(1.0f + t), 0.69314718056f, -0.69314718056f);
}
__device__ __forceinline__ short8 mk8(unsigned a, unsigned b, unsigned c, unsigned d) {
    union { unsigned u[4]; short8 s; } t;
    t.u[0] = a; t.u[1] = b; t.u[2] = c; t.u[3] = d;
    return t.s;
}

// ---------------------------------------------------------------------------
// Kernel 1: y = x @ in2f_w via bf16 MFMA (blocks 0..63, unchanged).
// Block 64: prep fw1T bf16 table in workspace: [f][g0..63], bias col @ g=50,
// zeros g=51..63 -> dense1 A-frags become single aligned dwordx4 global loads.
// ---------------------------------------------------------------------------
__global__ __launch_bounds__(256) void in2f_mfma2(const float* __restrict__ x,
                                                  const float* __restrict__ w,
                                                  unsigned short* __restrict__ y,
                                                  const float* __restrict__ fw1,
                                                  const float* __restrict__ fb1,
                                                  unsigned short* __restrict__ fw1t) {
    const int tid = threadIdx.x;
    if (blockIdx.x == 64) {
        for (int idx = tid; idx < 128 * 64; idx += 256) {
            int f = idx >> 6, g = idx & 63;
            float v = (g < Gdim) ? fw1[g * 128 + f] : ((g == Gdim) ? fb1[f] : 0.0f);
            fw1t[idx] = f2bf_u(v);
        }
        return;
    }
    __shared__ short sWT[128 * 132];   // w^T[f][i]
    __shared__ short sX [128 * 132];   // x[row][i]

#pragma unroll 4
    for (int k = 0; k < 32; ++k) {
        int idx = tid + k * 256;
        float2 v = *(const float2*)(w + 2 * idx);
        int i = idx >> 6;
        int f = (2 * idx) & 127;
        sWT[f * 132 + i]       = (short)f2bf_u(v.x);
        sWT[(f + 1) * 132 + i] = (short)f2bf_u(v.y);
    }
    const float* xb = x + (size_t)blockIdx.x * (128 * 128);
#pragma unroll 4
    for (int k = 0; k < 32; ++k) {
        int idx = tid + k * 256;
        float2 v = *(const float2*)(xb + 2 * idx);
        int row = idx >> 6;
        int i = (2 * idx) & 127;
        *(unsigned*)&sX[row * 132 + i] = pk2bf(v.x, v.y);
    }
    __syncthreads();

    const int wv = tid >> 6, lane = tid & 63, lm = lane & 31, lh = lane >> 5;
    floatx16 acc[4];
#pragma unroll
    for (int jt = 0; jt < 4; ++jt)
#pragma unroll
        for (int e = 0; e < 16; ++e) acc[jt][e] = 0.0f;

#pragma unroll
    for (int ks = 0; ks < 8; ++ks) {
        int g0 = ks * 16 + lh * 8;
        const short* ap = &sX[(wv * 32 + lm) * 132 + g0];
        uint2 a0 = *(const uint2*)ap;
        uint2 a1 = *(const uint2*)(ap + 4);
        short8 a = mk8(a0.x, a0.y, a1.x, a1.y);
#pragma unroll
        for (int jt = 0; jt < 4; ++jt) {
            const short* bp = &sWT[(jt * 32 + lm) * 132 + g0];
            uint2 b0 = *(const uint2*)bp;
            uint2 b1 = *(const uint2*)(bp + 4);
            acc[jt] = __builtin_amdgcn_mfma_f32_32x32x16_bf16(
                a, mk8(b0.x, b0.y, b1.x, b1.y), acc[jt], 0, 0, 0);
        }
    }
    const int rbase = blockIdx.x * 128 + wv * 32;
#pragma unroll
    for (int jt = 0; jt < 4; ++jt)
#pragma unroll
        for (int r = 0; r < 16; ++r) {
            int row = rbase + (r & 3) + 8 * (r >> 2) + 4 * lh;
            y[(size_t)row * 128 + jt * 32 + lm] = f2bf_u(acc[jt][r]);
        }
}

// ---------------------------------------------------------------------------
// Kernel 2 v5: occupancy 4 blocks/CU.
//  - sFw1 dropped from LDS: dense1 A-frags = single dwordx4 loads from the
//    pre-transposed bf16 fw1T table (16 KB, L2-resident).
//  - sFw2 back to padded stride 132 (2-way free on read AND staging write;
//    the v4 XOR swizzle lost a bit above the bank field -> 4-way, reverted).
//  - LDS 35840 B -> 4 blocks/CU; __launch_bounds__(256,4) pins VGPR <= 128.
//  - grid 2048 x exactly 2 bodies = 2 clean residency rounds.
// ---------------------------------------------------------------------------
#define SF2 132     // sFw2 stride (shorts): 66 dw -> 2-way free
#define NSP 4096    // total super-pairs (B*A/2)
#define GRID2 2048

struct FijRegs { float2 p[13]; };

__device__ __forceinline__ FijRegs load_fij(const float* __restrict__ f_ij,
                                            int sp, int row, int lh) {
    FijRegs F;
    const float* base = f_ij + (size_t)sp * (2 * Ndim * Gdim) + row * Gdim;
#pragma unroll
    for (int ks = 0; ks < 3; ++ks) {
        int g0 = 16 * ks + 8 * lh;
#pragma unroll
        for (int j = 0; j < 4; ++j)
            F.p[ks * 4 + j] = *(const float2*)(base + g0 + 2 * j);
    }
    F.p[12] = *(const float2*)(base + 48);   // both lh halves: g=48,49
    return F;
}

__device__ __forceinline__ void cf_body(
    int sp, int par, const FijRegs& F, int nsp, FijRegs& Fn,
    const float* __restrict__ f_ij, const float* __restrict__ r_ij,
    const float* __restrict__ mask, const int* __restrict__ nbr,
    const unsigned short* __restrict__ fw1t,
    const unsigned short* __restrict__ ybf, float* __restrict__ out,
    float4 fb2v, const short* sFw2,
    float (*sRed)[2][128], int wv, int lm, int lh, int row)
{
    // ---- convert this iteration's f_ij fragments (bf16, MFMA layout) ----
    short8 bfr[4];
#pragma unroll
    for (int ks = 0; ks < 3; ++ks)
        bfr[ks] = mk8(pk2bf(F.p[ks*4+0].x, F.p[ks*4+0].y),
                      pk2bf(F.p[ks*4+1].x, F.p[ks*4+1].y),
                      pk2bf(F.p[ks*4+2].x, F.p[ks*4+2].y),
                      pk2bf(F.p[ks*4+3].x, F.p[ks*4+3].y));
    {
        // ks=3: lh=0 holds g=48,49, bias 1.0 at g=50, zeros; lh=1 all zero
        unsigned u0 = lh ? 0u : pk2bf(F.p[12].x, F.p[12].y);
        unsigned u1 = lh ? 0u : 0x00003F80u;
        bfr[3] = mk8(u0, u1, 0u, 0u);
    }
    // ---- prefetch next super-pair's f_ij (lands during dense1/2) ----
    if (nsp >= 0) Fn = load_fij(f_ij, nsp, row, lh);

    // ---- dense1: A = fw1T (global dwordx4, L2-hot), B = f_ij (regs) ----
    unsigned A2[8][4];
#pragma unroll
    for (int ft = 0; ft < 4; ++ft) {
        floatx16 a1;
#pragma unroll
        for (int e = 0; e < 16; ++e) a1[e] = 0.0f;
        const unsigned short* fwp = fw1t + ((ft * 32 + lm) * 64 + lh * 8);
#pragma unroll
        for (int ks = 0; ks < 4; ++ks) {
            short8 a = *(const short8*)(fwp + ks * 16);
            a1 = __builtin_amdgcn_mfma_f32_32x32x16_bf16(a, bfr[ks], a1, 0, 0, 0);
        }
        unsigned P[8], X[8];
#pragma unroll
        for (int q = 0; q < 8; ++q)
            P[q] = pk2bf(sspf(a1[2 * q]), sspf(a1[2 * q + 1]));
#pragma unroll
        for (int q = 0; q < 8; ++q) X[q] = (unsigned)__shfl_xor((int)P[q], 32);
        A2[2*ft][0]   = lh ? X[2] : P[0];  A2[2*ft][1]   = lh ? X[3] : P[1];
        A2[2*ft][2]   = lh ? P[2] : X[0];  A2[2*ft][3]   = lh ? P[3] : X[1];
        A2[2*ft+1][0] = lh ? X[6] : P[4];  A2[2*ft+1][1] = lh ? X[7] : P[5];
        A2[2*ft+1][2] = lh ? P[6] : X[4];  A2[2*ft+1][3] = lh ? P[7] : X[5];
    }

    // ---- dense2: A = W1 (regs), B = fw2T (LDS, padded stride) ----
    floatx16 acc2[4];
#pragma unroll
    for (int jt = 0; jt < 4; ++jt)
#pragma unroll
        for (int e = 0; e < 16; ++e) acc2[jt][e] = 0.0f;
#pragma unroll
    for (int ks = 0; ks < 8; ++ks) {
        short8 a = mk8(A2[ks][0], A2[ks][1], A2[ks][2], A2[ks][3]);
#pragma unroll
        for (int jt = 0; jt < 4; ++jt) {
            const short* bp = &sFw2[(jt * 32 + lm) * SF2 + ks * 16 + lh * 8];
            uint2 b0 = *(const uint2*)bp;
            uint2 b1 = *(const uint2*)(bp + 4);
            acc2[jt] = __builtin_amdgcn_mfma_f32_32x32x16_bf16(
                a, mk8(b0.x, b0.y, b1.x, b1.y), acc2[jt], 0, 0, 0);
        }
    }

    // ---- cutoff*mask + neighbor indices: broadcast loads, in-reg cos ----
    const int site = sp * 2 + (wv >> 1);
    float cmv[16]; int nbv[16];
#pragma unroll
    for (int rq = 0; rq < 4; ++rq) {
        int off = site * Ndim + (wv & 1) * 32 + rq * 8 + lh * 4;
        float4 r4 = *(const float4*)(r_ij + off);
        float4 m4 = *(const float4*)(mask + off);
        int4   n4 = *(const int4*)(nbr + off);
        float rr[4] = { r4.x, r4.y, r4.z, r4.w };
        float mm[4] = { m4.x, m4.y, m4.z, m4.w };
        int   nn[4] = { n4.x, n4.y, n4.z, n4.w };
#pragma unroll
        for (int j = 0; j < 4; ++j) {
            float c = 0.5f * (__cosf(rr[j] * 0.62831853071796f) + 1.0f);
            c = (rr[j] < 5.0f) ? c : 0.0f;
            cmv[rq * 4 + j] = c * mm[j];
            nbv[rq * 4 + j] = nn[j];
        }
    }

    // ---- epilogue: out[f] += cm[n]*(W2[n,f]+fb2[f])*y[nbr[n],f] ----
    const int bofs = (site >> 8) * Adim;
    float part[4] = {0.f, 0.f, 0.f, 0.f};
#pragma unroll
    for (int r = 0; r < 16; ++r) {
        float cm = cmv[r];
        const unsigned short* yr = ybf + (size_t)(bofs + nbv[r]) * Fdim;
#pragma unroll
        for (int jt = 0; jt < 4; ++jt) {
            float fb2j = (jt == 0) ? fb2v.x : (jt == 1) ? fb2v.y
                       : (jt == 2) ? fb2v.z : fb2v.w;
            float t = (acc2[jt][r] + fb2j) * cm;          // add + mul
            part[jt] = fmaf(t, bf2f(yr[jt * 32 + lm]), part[jt]);  // shift + fma
        }
    }
#pragma unroll
    for (int jt = 0; jt < 4; ++jt) part[jt] += __shfl_xor(part[jt], 32);

    const int s = wv >> 1;
    if (wv & 1) {
#pragma unroll
        for (int k = 0; k < 2; ++k)
            sRed[par][s][(2 * lh + k) * 32 + lm] = part[2 * lh + k];
    }
    __syncthreads();   // only barrier per iteration (sRed parity-dbuf'd)
    if (!(wv & 1)) {
#pragma unroll
        for (int k = 0; k < 2; ++k) {
            int jt = 2 * lh + k;
            int f = jt * 32 + lm;
            out[(size_t)site * Fdim + f] = part[jt] + sRed[par][s][f];
        }
    }
}

__global__ __launch_bounds__(256, 4) void cfconv_mfma5(
    const float* __restrict__ r_ij, const float* __restrict__ f_ij,
    const float* __restrict__ mask, const int* __restrict__ nbr,
    const unsigned short* __restrict__ fw1t, const float* __restrict__ fw2,
    const float* __restrict__ fb2,
    const unsigned short* __restrict__ ybf, float* __restrict__ out)
{
    __shared__ short sFw2[128 * SF2];       // 33792 B: fw2T[f][h], padded
    __shared__ float sRed[2][2][128];       //  2048 B: parity x site x f
    // total 35840 B -> 4 blocks/CU

    const int tid = threadIdx.x, wv = tid >> 6, lane = tid & 63;
    const int lm = lane & 31, lh = lane >> 5;
    const int bid = blockIdx.x;
    const int row = wv * 32 + lm;

    FijRegs FA = load_fij(f_ij, bid, row, lh);   // issue before staging

    // stage fw2T padded: write addr = f*264 B -> bank 2f mod 32, 2-way free
    for (int idx = tid; idx < 128 * 128; idx += 256) {
        int h = idx >> 7, f = idx & 127;
        sFw2[f * SF2 + h] = (short)f2bf_u(fw2[idx]);
    }
    float4 fb2v;
    fb2v.x = fb2[lm]; fb2v.y = fb2[32 + lm]; fb2v.z = fb2[64 + lm]; fb2v.w = fb2[96 + lm];
    __syncthreads();

    const int sp1 = bid + GRID2;
    FijRegs FB;
    cf_body(bid, 0, FA, sp1, FB, f_ij, r_ij, mask, nbr, fw1t, ybf, out,
            fb2v, sFw2, sRed, wv, lm, lh, row);
    cf_body(sp1, 1, FB, -1, FA, f_ij, r_ij, mask, nbr, fw1t, ybf, out,
            fb2v, sFw2, sRed, wv, lm, lh, row);
}

// ---------------------------------------------------------------------------
extern "C" void kernel_launch(void* const* d_in, const int* in_sizes, int n_in,
                              void* d_out, int out_size, void* d_ws, size_t ws_size,
                              hipStream_t stream) {
    const float* x      = (const float*)d_in[0];
    const float* r_ij   = (const float*)d_in[1];
    const float* f_ij   = (const float*)d_in[2];
    const float* mask   = (const float*)d_in[3];
    const int*   nbr    = (const int*)d_in[4];
    const float* in2f_w = (const float*)d_in[5];
    const float* fw1    = (const float*)d_in[6];
    const float* fb1    = (const float*)d_in[7];
    const float* fw2    = (const float*)d_in[8];
    const float* fb2    = (const float*)d_in[9];
    float* out = (float*)d_out;
    unsigned short* y    = (unsigned short*)d_ws;                 // 2 MB bf16 y
    unsigned short* fw1t = (unsigned short*)((char*)d_ws + (size_t)(Bdim*Adim*Fdim)*2); // 16 KB table

    in2f_mfma2<<<65, 256, 0, stream>>>(x, in2f_w, y, fw1, fb1, fw1t);
    cfconv_mfma5<<<GRID2, 256, 0, stream>>>(r_ij, f_ij, mask, nbr,
                                            fw1t, fw2, fb2, y, out);
}